// Round 1
// baseline (1837.370 us; speedup 1.0000x reference)
//
#include <hip/hip_runtime.h>

typedef _Float16 half8 __attribute__((ext_vector_type(8)));
typedef float f32x4 __attribute__((ext_vector_type(4)));

#define HDIM 768
#define NTOK 32768

// ---- workspace layout (bytes) ----
static constexpr size_t WX_OFF   = 0;                   // int8  [NTOK*HDIM] = 25165824
static constexpr size_t WINT_OFF = 25165824;            // f16   [HDIM*HDIM] = 1179648 B
static constexpr size_t RS1_OFF  = WINT_OFF + 1179648;  // double[768]
static constexpr size_t RS2_OFF  = RS1_OFF + 6144;      // double[768]
static constexpr size_t BS_OFF   = RS2_OFF + 6144;      // float [768] bias_scale
static constexpr size_t BINT_OFF = BS_OFF + 3072;       // int   [768] b_int
static constexpr size_t LNBI_OFF = BINT_OFF + 3072;     // int   [768] LN bias_int
static constexpr size_t SFO_OFF  = LNBI_OFF + 3072;     // float [768] sf_out
static constexpr size_t SC_OFF   = SFO_OFF + 3072;      // scalars: [0]min1 [1]max1 [2]min2 [3]max2 [4]shift [5]s [6]s2
static constexpr size_t RSM1_OFF = SC_OFF + 64;         // double rs_m1

// sortable-uint encoding of float for atomic min/max
__device__ __forceinline__ unsigned fenc(float f) {
    unsigned u = __float_as_uint(f);
    return (u >> 31) ? ~u : (u | 0x80000000u);
}
__device__ __forceinline__ float fdec(unsigned e) {
    unsigned u = (e >> 31) ? (e & 0x7fffffffu) : ~e;
    return __uint_as_float(u);
}

// block reduce (sum) for 3-wave blocks (192 threads), result broadcast to all
__device__ __forceinline__ long long blockReduceLL(long long v, long long* sh, int tid) {
    int wave = tid >> 6, lane = tid & 63;
    #pragma unroll
    for (int off = 32; off; off >>= 1) v += __shfl_down(v, off);
    __syncthreads();
    if (lane == 0) sh[wave] = v;
    __syncthreads();
    return sh[0] + sh[1] + sh[2];
}

// ============ K0: weight quantization + per-channel tables + scalar init ============
__global__ __launch_bounds__(256) void k0_prep(const float* __restrict__ W,
                                               const float* __restrict__ bias,
                                               const float* __restrict__ ln_w,
                                               const float* __restrict__ ln_b,
                                               const float* __restrict__ phsf,
                                               char* __restrict__ ws) {
    int o = blockIdx.x, tid = threadIdx.x;
    __shared__ float red[256];
    __shared__ float fc_sh;
    float m = 0.f;
    for (int j = tid; j < HDIM; j += 256) m = fmaxf(m, fabsf(W[(size_t)o * HDIM + j]));
    red[tid] = m;
    __syncthreads();
    for (int s = 128; s; s >>= 1) { if (tid < s) red[tid] = fmaxf(red[tid], red[tid + s]); __syncthreads(); }
    if (tid == 0) {
        float fc = fmaxf(red[0], 1e-8f) / 127.0f;     // _sym_scale(8,...)
        float hsf = *phsf;
        float bs = fc * hsf;
        fc_sh = fc;
        ((float*)(ws + BS_OFF))[o] = bs;
        ((int*)(ws + BINT_OFF))[o] = (int)rintf(bias[o] / bs);   // _sym_quant(bias,32)
        float sf = sqrtf(768.0f) / 1073741824.0f;                // sqrt(H)/2^30
        float lw = ln_w[o], lb = ln_b[o];
        ((int*)(ws + LNBI_OFF))[o] = (int)floorf((lb / lw) / sf);
        ((float*)(ws + SFO_OFF))[o] = sf * lw;
    }
    __syncthreads();
    float fc = fc_sh;
    _Float16* w16 = (_Float16*)(ws + WINT_OFF);
    for (int j = tid; j < HDIM; j += 256) {
        float q = rintf(W[(size_t)o * HDIM + j] / fc);
        q = fminf(fmaxf(q, -127.f), 126.f);           // clip [-n, n-1]
        w16[(size_t)o * HDIM + j] = (_Float16)q;
    }
    if (blockIdx.x == 0 && tid < 8) {
        unsigned* sc = (unsigned*)(ws + SC_OFF);
        unsigned v = 0u;
        if (tid == 0 || tid == 2) v = 0xFFFFFFFFu;    // min slots
        sc[tid] = v;                                   // max slots + shift -> 0
    }
}

// ============ K1: int GEMM (exact, via f16 MFMA) + bias + x_act min/max + wx ============
#define TM 32
__global__ __launch_bounds__(256) void k1_gemm(const float* __restrict__ hs_in,
                                               const float* __restrict__ inp,
                                               const float* __restrict__ phsf,
                                               const float* __restrict__ pisf,
                                               char* __restrict__ ws,
                                               int* __restrict__ accOut) {
    __shared__ _Float16 xs[TM][HDIM + 8];   // pad 8 halves: 2-way-conflict-free b128 reads
    __shared__ float rmn[4], rmx[4];
    int tid = threadIdx.x;
    int t0 = blockIdx.x * TM;
    float inv_hsf = 1.0f / *phsf;
    float inv_isf = 1.0f / *pisf;

    // stage x tile: 32 rows x 768 f32 -> f16 integers
    #pragma unroll
    for (int it = 0; it < 12; ++it) {
        int chunk = tid + 256 * it;           // 0..3071 chunks of 8 elems
        int r = chunk / 96, c8 = chunk % 96;
        const float4* src = (const float4*)(hs_in + (size_t)(t0 + r) * HDIM + c8 * 8);
        float4 a = src[0], b = src[1];
        half8 hv;
        hv[0] = (_Float16)rintf(a.x * inv_hsf); hv[1] = (_Float16)rintf(a.y * inv_hsf);
        hv[2] = (_Float16)rintf(a.z * inv_hsf); hv[3] = (_Float16)rintf(a.w * inv_hsf);
        hv[4] = (_Float16)rintf(b.x * inv_hsf); hv[5] = (_Float16)rintf(b.y * inv_hsf);
        hv[6] = (_Float16)rintf(b.z * inv_hsf); hv[7] = (_Float16)rintf(b.w * inv_hsf);
        *(half8*)&xs[r][c8 * 8] = hv;
    }
    __syncthreads();

    int wave = tid >> 6, lane = tid & 63;
    int wrow = lane & 15, wkg = lane >> 4;
    const _Float16* w16 = (const _Float16*)(ws + WINT_OFF);
    const float* bscale = (const float*)(ws + BS_OFF);
    const int* bint = (const int*)(ws + BINT_OFF);
    char* wx = (char*)(ws + WX_OFF);
    float lmn = 3.402823466e38f, lmx = -3.402823466e38f;

    for (int oc = 0; oc < 3; ++oc) {          // each wave: 192 output channels
        int o0 = wave * 192 + oc * 64;
        f32x4 acc[2][4] = {};
        for (int kc = 0; kc < 24; ++kc) {
            int k0 = kc * 32;
            half8 a0 = *(const half8*)&xs[wrow][k0 + wkg * 8];
            half8 a1 = *(const half8*)&xs[16 + wrow][k0 + wkg * 8];
            #pragma unroll
            for (int nf = 0; nf < 4; ++nf) {
                half8 bF = *(const half8*)&w16[(size_t)(o0 + nf * 16 + wrow) * HDIM + k0 + wkg * 8];
                acc[0][nf] = __builtin_amdgcn_mfma_f32_16x16x32_f16(a0, bF, acc[0][nf], 0, 0, 0);
                acc[1][nf] = __builtin_amdgcn_mfma_f32_16x16x32_f16(a1, bF, acc[1][nf], 0, 0, 0);
            }
        }
        // epilogue: bias add, store acc (int32), x_act min/max, wx store
        #pragma unroll
        for (int mi = 0; mi < 2; ++mi)
            #pragma unroll
            for (int nf = 0; nf < 4; ++nf)
                #pragma unroll
                for (int r = 0; r < 4; ++r) {
                    int t = t0 + mi * 16 + wkg * 4 + r;
                    int o = o0 + nf * 16 + wrow;
                    int a = (int)acc[mi][nf][r] + bint[o];
                    size_t idx = (size_t)t * HDIM + o;
                    accOut[idx] = a;
                    float xin = inp[idx];
                    float xa = (float)a * bscale[o] + xin;
                    lmn = fminf(lmn, xa);
                    lmx = fmaxf(lmx, xa);
                    wx[idx] = (char)rintf(xin * inv_isf);
                }
    }
    #pragma unroll
    for (int off = 32; off; off >>= 1) {
        lmn = fminf(lmn, __shfl_down(lmn, off));
        lmx = fmaxf(lmx, __shfl_down(lmx, off));
    }
    if (lane == 0) { rmn[wave] = lmn; rmx[wave] = lmx; }
    __syncthreads();
    if (tid == 0) {
        float mn = fminf(fminf(rmn[0], rmn[1]), fminf(rmn[2], rmn[3]));
        float mx = fmaxf(fmaxf(rmx[0], rmx[1]), fmaxf(rmx[2], rmx[3]));
        unsigned* sc = (unsigned*)(ws + SC_OFF);
        atomicMin(&sc[0], fenc(mn));
        atomicMax(&sc[1], fenc(mx));
    }
}

// ============ K2: finalize ln_in_scale s + frexp tables ============
__global__ __launch_bounds__(256) void k2_scale1(const float* __restrict__ pisf, char* __restrict__ ws) {
    __shared__ float s_sh;
    unsigned* sc = (unsigned*)(ws + SC_OFF);
    if (threadIdx.x == 0) {
        float mn = fdec(sc[0]), mx = fdec(sc[1]);
        float s = fmaxf(fmaxf(fabsf(mn), fabsf(mx)), 1e-8f) / 2097151.0f;  // n = 2^21-1
        ((float*)sc)[5] = s;
        s_sh = s;
        double r = (double)(*pisf) / (double)s;
        int ex; double mant = frexp(r, &ex);
        double m1 = floor(mant * 2147483648.0 + 0.5);
        ((double*)(ws + RSM1_OFF))[0] = m1 * exp2((double)(ex - 31));  // m1 * 2^-(31-ex)
    }
    __syncthreads();
    float s = s_sh;
    const float* bs = (const float*)(ws + BS_OFF);
    double* rs1 = (double*)(ws + RS1_OFF);
    for (int o = threadIdx.x; o < HDIM; o += 256) {
        double r = (double)bs[o] / (double)s;
        int ex; double mant = frexp(r, &ex);
        double m = floor(mant * 2147483648.0 + 0.5);
        rs1[o] = m * exp2((double)(ex - 31));
    }
}

// ============ K3: per-row fixed-point requant (22-bit), mean, var0, shift ============
__global__ __launch_bounds__(192) void k3_rows(char* __restrict__ ws, int* __restrict__ buf) {
    __shared__ long long sh[3];
    int row = blockIdx.x, tid = threadIdx.x;
    size_t base = (size_t)row * HDIM;
    int4 a = ((const int4*)(buf + base))[tid];
    int w4 = ((const int*)(ws + WX_OFF + base))[tid];
    const double* rs1 = (const double*)(ws + RS1_OFF);
    double rsm1 = *(const double*)(ws + RSM1_OFF);
    int o0 = tid * 4;
    int av[4] = {a.x, a.y, a.z, a.w};
    int q[4];
    long long sum = 0;
    #pragma unroll
    for (int j = 0; j < 4; ++j) {
        double q1 = rint((double)av[j] * rs1[o0 + j]);
        int wxj = (int)(char)(w4 >> (8 * j));
        double q2 = rint((double)wxj * rsm1);
        double qq = q1 + q2;
        qq = fmin(fmax(qq, -2097152.0), 2097151.0);   // clip [-2^21, 2^21-1]
        q[j] = (int)qq;
        sum += q[j];
    }
    sum = blockReduceLL(sum, sh, tid);
    int mean = (int)rint((double)sum / 768.0);
    long long var0 = 0;
    #pragma unroll
    for (int j = 0; j < 4; ++j) { q[j] -= mean; var0 += (long long)q[j] * (long long)q[j]; }
    var0 = blockReduceLL(var0, sh, tid);
    if (tid == 0) {
        double v = (double)(var0 < 1 ? 1LL : var0);
        int sr = (int)ceil(0.5 * log2(v) - 16.0);     // ceil(log2(sqrt(v/2^32)))
        if (sr > 0) atomicMax(((int*)(ws + SC_OFF)) + 4, sr);
    }
    int4 y = {q[0], q[1], q[2], q[3]};
    ((int4*)(buf + base))[tid] = y;
}

// ============ K4: per-row IntLayerNorm normalize, hs min/max ============
__global__ __launch_bounds__(192) void k4_rows(char* __restrict__ ws, int* __restrict__ buf) {
    __shared__ long long sh[3];
    __shared__ float fmn[3], fmx[3];
    int row = blockIdx.x, tid = threadIdx.x;
    size_t base = (size_t)row * HDIM;
    int4 y = ((const int4*)(buf + base))[tid];
    int shift = *(((const int*)(ws + SC_OFF)) + 4);
    int yv[4] = {y.x, y.y, y.z, y.w};
    long long var = 0;
    #pragma unroll
    for (int j = 0; j < 4; ++j) { int ysh = yv[j] >> shift; var += (long long)ysh * (long long)ysh; }
    var = blockReduceLL(var, sh, tid);
    double std_int = floor(sqrt((double)var)) * (double)(1LL << shift);
    if (std_int < 1.0) std_int = 1.0;                 // degenerate-row guard
    long long factor = (long long)floor(2147483648.0 / std_int);
    const int* lnbi = (const int*)(ws + LNBI_OFF);
    const float* sfo = (const float*)(ws + SFO_OFF);
    int o0 = tid * 4;
    float lmn = 3.402823466e38f, lmx = -3.402823466e38f;
    int y2[4];
    #pragma unroll
    for (int j = 0; j < 4; ++j) {
        long long t = ((long long)yv[j] * factor) >> 1;   // floor(y*factor/2)
        int v2 = (int)t + lnbi[o0 + j];
        y2[j] = v2;
        float h = (float)v2 * sfo[o0 + j];
        lmn = fminf(lmn, h);
        lmx = fmaxf(lmx, h);
    }
    int4 w = {y2[0], y2[1], y2[2], y2[3]};
    ((int4*)(buf + base))[tid] = w;
    int wave = tid >> 6, lane = tid & 63;
    #pragma unroll
    for (int off = 32; off; off >>= 1) {
        lmn = fminf(lmn, __shfl_down(lmn, off));
        lmx = fmaxf(lmx, __shfl_down(lmx, off));
    }
    if (lane == 0) { fmn[wave] = lmn; fmx[wave] = lmx; }
    __syncthreads();
    if (tid == 0) {
        float mn = fminf(fminf(fmn[0], fmn[1]), fmn[2]);
        float mx = fmaxf(fmaxf(fmx[0], fmx[1]), fmx[2]);
        unsigned* sc = (unsigned*)(ws + SC_OFF);
        atomicMin(&sc[2], fenc(mn));
        atomicMax(&sc[3], fenc(mx));
    }
}

// ============ K5: finalize s2 + frexp tables ============
__global__ __launch_bounds__(256) void k5_scale2(char* __restrict__ ws) {
    __shared__ float s_sh;
    unsigned* sc = (unsigned*)(ws + SC_OFF);
    if (threadIdx.x == 0) {
        float mn = fdec(sc[2]), mx = fdec(sc[3]);
        float s2 = fmaxf(fmaxf(fabsf(mn), fabsf(mx)), 1e-8f) / 127.0f;
        ((float*)sc)[6] = s2;
        s_sh = s2;
    }
    __syncthreads();
    float s2 = s_sh;
    const float* sfo = (const float*)(ws + SFO_OFF);
    double* rs2 = (double*)(ws + RS2_OFF);
    for (int o = threadIdx.x; o < HDIM; o += 256) {
        double r = (double)sfo[o] / (double)s2;
        int ex; double mant = frexp(r, &ex);
        double m = floor(mant * 2147483648.0 + 0.5);
        rs2[o] = m * exp2((double)(ex - 31));
    }
}

// ============ K6: 8-bit requant + output write ============
__global__ __launch_bounds__(256) void k6_out(char* __restrict__ ws, float* __restrict__ out) {
    int idx4 = blockIdx.x * 256 + threadIdx.x;
    int4 y = ((const int4*)out)[idx4];
    const double* rs2 = (const double*)(ws + RS2_OFF);
    float s2 = ((const float*)(ws + SC_OFF))[6];
    int base = idx4 * 4;
    int o0 = base % HDIM;   // base%4==0 and 768%4==0 -> no row crossing within int4
    int yv[4] = {y.x, y.y, y.z, y.w};
    float4 r;
    float* rp = &r.x;
    #pragma unroll
    for (int j = 0; j < 4; ++j) {
        double q = rint((double)yv[j] * rs2[o0 + j]);
        q = fmin(fmax(q, -128.0), 127.0);
        rp[j] = (float)q * s2;
    }
    ((float4*)out)[idx4] = r;
    if (idx4 == 0) out[(size_t)NTOK * HDIM] = s2;
}

extern "C" void kernel_launch(void* const* d_in, const int* in_sizes, int n_in,
                              void* d_out, int out_size, void* d_ws, size_t ws_size,
                              hipStream_t stream) {
    const float* hs   = (const float*)d_in[0];
    const float* phsf = (const float*)d_in[1];
    const float* inp  = (const float*)d_in[2];
    const float* pisf = (const float*)d_in[3];
    const float* W    = (const float*)d_in[4];
    const float* bias = (const float*)d_in[5];
    const float* ln_w = (const float*)d_in[6];
    const float* ln_b = (const float*)d_in[7];
    char* ws = (char*)d_ws;
    float* out = (float*)d_out;
    int* buf = (int*)d_out;   // d_out doubles as the 100MB int32 intermediate buffer

    k0_prep<<<HDIM, 256, 0, stream>>>(W, bias, ln_w, ln_b, phsf, ws);
    k1_gemm<<<NTOK / TM, 256, 0, stream>>>(hs, inp, phsf, pisf, ws, buf);
    k2_scale1<<<1, 256, 0, stream>>>(pisf, ws);
    k3_rows<<<NTOK, 192, 0, stream>>>(ws, buf);
    k4_rows<<<NTOK, 192, 0, stream>>>(ws, buf);
    k5_scale2<<<1, 256, 0, stream>>>(ws);
    k6_out<<<NTOK * HDIM / 1024, 256, 0, stream>>>(ws, out);
}

// Round 2
// 836.187 us; speedup vs baseline: 2.1973x; 2.1973x over previous
//
#include <hip/hip_runtime.h>

typedef _Float16 half8 __attribute__((ext_vector_type(8)));
typedef float f32x4 __attribute__((ext_vector_type(4)));

#define HDIM 768
#define NTOK 32768

// ---- workspace layout (bytes) ----
static constexpr size_t WX_OFF   = 0;                   // int8  [NTOK*HDIM] = 25165824
static constexpr size_t WINT_OFF = 25165824;            // f16   [HDIM*HDIM] = 1179648 B
static constexpr size_t RS1_OFF  = WINT_OFF + 1179648;  // double[768]
static constexpr size_t RS2_OFF  = RS1_OFF + 6144;      // double[768]
static constexpr size_t BS_OFF   = RS2_OFF + 6144;      // float [768] bias_scale
static constexpr size_t BINT_OFF = BS_OFF + 3072;       // int   [768] b_int
static constexpr size_t LNBI_OFF = BINT_OFF + 3072;     // int   [768] LN bias_int
static constexpr size_t SFO_OFF  = LNBI_OFF + 3072;     // float [768] sf_out
static constexpr size_t SC_OFF   = SFO_OFF + 3072;      // scalars: [0]min1 [1]max1 [2]min2 [3]max2 [4]shift [5]s [6]s2
static constexpr size_t RSM1_OFF = SC_OFF + 64;         // double rs_m1

// sortable-uint encoding of float for atomic min/max
__device__ __forceinline__ unsigned fenc(float f) {
    unsigned u = __float_as_uint(f);
    return (u >> 31) ? ~u : (u | 0x80000000u);
}
__device__ __forceinline__ float fdec(unsigned e) {
    unsigned u = (e >> 31) ? (e & 0x7fffffffu) : ~e;
    return __uint_as_float(u);
}

// ============ K0: weight quantization + per-channel tables + scalar init ============
__global__ __launch_bounds__(256) void k0_prep(const float* __restrict__ W,
                                               const float* __restrict__ bias,
                                               const float* __restrict__ ln_w,
                                               const float* __restrict__ ln_b,
                                               const float* __restrict__ phsf,
                                               char* __restrict__ ws) {
    int o = blockIdx.x, tid = threadIdx.x;
    __shared__ float red[256];
    __shared__ float fc_sh;
    float m = 0.f;
    for (int j = tid; j < HDIM; j += 256) m = fmaxf(m, fabsf(W[(size_t)o * HDIM + j]));
    red[tid] = m;
    __syncthreads();
    for (int s = 128; s; s >>= 1) { if (tid < s) red[tid] = fmaxf(red[tid], red[tid + s]); __syncthreads(); }
    if (tid == 0) {
        float fc = fmaxf(red[0], 1e-8f) / 127.0f;     // _sym_scale(8,...)
        float hsf = *phsf;
        float bs = fc * hsf;
        fc_sh = fc;
        ((float*)(ws + BS_OFF))[o] = bs;
        ((int*)(ws + BINT_OFF))[o] = (int)rintf(bias[o] / bs);   // _sym_quant(bias,32)
        float sf = sqrtf(768.0f) / 1073741824.0f;                // sqrt(H)/2^30
        float lw = ln_w[o], lb = ln_b[o];
        ((int*)(ws + LNBI_OFF))[o] = (int)floorf((lb / lw) / sf);
        ((float*)(ws + SFO_OFF))[o] = sf * lw;
    }
    __syncthreads();
    float fc = fc_sh;
    _Float16* w16 = (_Float16*)(ws + WINT_OFF);
    for (int j = tid; j < HDIM; j += 256) {
        float q = rintf(W[(size_t)o * HDIM + j] / fc);
        q = fminf(fmaxf(q, -127.f), 126.f);           // clip [-n, n-1]
        w16[(size_t)o * HDIM + j] = (_Float16)q;
    }
    if (blockIdx.x == 0 && tid < 8) {
        unsigned* sc = (unsigned*)(ws + SC_OFF);
        unsigned v = 0u;
        if (tid == 0 || tid == 2) v = 0xFFFFFFFFu;    // min slots
        sc[tid] = v;                                   // max slots + shift -> 0
    }
}

// ============ K1: int GEMM (exact, via f16 MFMA) + bias + x_act min/max + wx ============
#define TM 32
__global__ __launch_bounds__(256) void k1_gemm(const float* __restrict__ hs_in,
                                               const float* __restrict__ inp,
                                               const float* __restrict__ phsf,
                                               const float* __restrict__ pisf,
                                               char* __restrict__ ws,
                                               int* __restrict__ accOut) {
    __shared__ _Float16 xs[TM][HDIM + 8];   // pad 8 halves: 2-way-conflict-free b128 reads
    __shared__ float rmn[4], rmx[4];
    int tid = threadIdx.x;
    int t0 = blockIdx.x * TM;
    float inv_hsf = 1.0f / *phsf;
    float inv_isf = 1.0f / *pisf;

    // stage x tile: 32 rows x 768 f32 -> f16 integers
    #pragma unroll
    for (int it = 0; it < 12; ++it) {
        int chunk = tid + 256 * it;           // 0..3071 chunks of 8 elems
        int r = chunk / 96, c8 = chunk % 96;
        const float4* src = (const float4*)(hs_in + (size_t)(t0 + r) * HDIM + c8 * 8);
        float4 a = src[0], b = src[1];
        half8 hv;
        hv[0] = (_Float16)rintf(a.x * inv_hsf); hv[1] = (_Float16)rintf(a.y * inv_hsf);
        hv[2] = (_Float16)rintf(a.z * inv_hsf); hv[3] = (_Float16)rintf(a.w * inv_hsf);
        hv[4] = (_Float16)rintf(b.x * inv_hsf); hv[5] = (_Float16)rintf(b.y * inv_hsf);
        hv[6] = (_Float16)rintf(b.z * inv_hsf); hv[7] = (_Float16)rintf(b.w * inv_hsf);
        *(half8*)&xs[r][c8 * 8] = hv;
    }
    __syncthreads();

    int wave = tid >> 6, lane = tid & 63;
    int wrow = lane & 15, wkg = lane >> 4;
    const _Float16* w16 = (const _Float16*)(ws + WINT_OFF);
    const float* bscale = (const float*)(ws + BS_OFF);
    const int* bint = (const int*)(ws + BINT_OFF);
    char* wx = (char*)(ws + WX_OFF);
    float lmn = 3.402823466e38f, lmx = -3.402823466e38f;

    for (int oc = 0; oc < 3; ++oc) {          // each wave: 192 output channels
        int o0 = wave * 192 + oc * 64;
        f32x4 acc[2][4] = {};
        for (int kc = 0; kc < 24; ++kc) {
            int k0 = kc * 32;
            half8 a0 = *(const half8*)&xs[wrow][k0 + wkg * 8];
            half8 a1 = *(const half8*)&xs[16 + wrow][k0 + wkg * 8];
            #pragma unroll
            for (int nf = 0; nf < 4; ++nf) {
                half8 bF = *(const half8*)&w16[(size_t)(o0 + nf * 16 + wrow) * HDIM + k0 + wkg * 8];
                acc[0][nf] = __builtin_amdgcn_mfma_f32_16x16x32_f16(a0, bF, acc[0][nf], 0, 0, 0);
                acc[1][nf] = __builtin_amdgcn_mfma_f32_16x16x32_f16(a1, bF, acc[1][nf], 0, 0, 0);
            }
        }
        // epilogue: bias add, store acc (int32), x_act min/max, wx store
        #pragma unroll
        for (int mi = 0; mi < 2; ++mi)
            #pragma unroll
            for (int nf = 0; nf < 4; ++nf)
                #pragma unroll
                for (int r = 0; r < 4; ++r) {
                    int t = t0 + mi * 16 + wkg * 4 + r;
                    int o = o0 + nf * 16 + wrow;
                    int a = (int)acc[mi][nf][r] + bint[o];
                    size_t idx = (size_t)t * HDIM + o;
                    accOut[idx] = a;
                    float xin = inp[idx];
                    float xa = (float)a * bscale[o] + xin;
                    lmn = fminf(lmn, xa);
                    lmx = fmaxf(lmx, xa);
                    wx[idx] = (char)rintf(xin * inv_isf);
                }
    }
    #pragma unroll
    for (int off = 32; off; off >>= 1) {
        lmn = fminf(lmn, __shfl_down(lmn, off));
        lmx = fmaxf(lmx, __shfl_down(lmx, off));
    }
    if (lane == 0) { rmn[wave] = lmn; rmx[wave] = lmx; }
    __syncthreads();
    if (tid == 0) {
        float mn = fminf(fminf(rmn[0], rmn[1]), fminf(rmn[2], rmn[3]));
        float mx = fmaxf(fmaxf(rmx[0], rmx[1]), fmaxf(rmx[2], rmx[3]));
        volatile unsigned* sc = (volatile unsigned*)(ws + SC_OFF);
        unsigned emn = fenc(mn), emx = fenc(mx);
        // guarded atomics: min/max are monotone, stale reads only cause extra atomics
        if (emn < sc[0]) atomicMin((unsigned*)&sc[0], emn);
        if (emx > sc[1]) atomicMax((unsigned*)&sc[1], emx);
    }
}

// ============ K2: finalize ln_in_scale s + frexp tables ============
__global__ __launch_bounds__(256) void k2_scale1(const float* __restrict__ pisf, char* __restrict__ ws) {
    __shared__ float s_sh;
    unsigned* sc = (unsigned*)(ws + SC_OFF);
    if (threadIdx.x == 0) {
        float mn = fdec(sc[0]), mx = fdec(sc[1]);
        float s = fmaxf(fmaxf(fabsf(mn), fabsf(mx)), 1e-8f) / 2097151.0f;  // n = 2^21-1
        ((float*)sc)[5] = s;
        s_sh = s;
        double r = (double)(*pisf) / (double)s;
        int ex; double mant = frexp(r, &ex);
        double m1 = floor(mant * 2147483648.0 + 0.5);
        ((double*)(ws + RSM1_OFF))[0] = m1 * exp2((double)(ex - 31));  // m1 * 2^-(31-ex)
    }
    __syncthreads();
    float s = s_sh;
    const float* bs = (const float*)(ws + BS_OFF);
    double* rs1 = (double*)(ws + RS1_OFF);
    for (int o = threadIdx.x; o < HDIM; o += 256) {
        double r = (double)bs[o] / (double)s;
        int ex; double mant = frexp(r, &ex);
        double m = floor(mant * 2147483648.0 + 0.5);
        rs1[o] = m * exp2((double)(ex - 31));
    }
}

// ============ K3: wave-per-row fixed-point requant (22-bit), mean, var0, shift ============
// 4 waves/block, 4 rows/wave -> grid = NTOK/16 = 2048
__global__ __launch_bounds__(256) void k3_rows(char* __restrict__ ws, int* __restrict__ buf) {
    int tid = threadIdx.x, lane = tid & 63, wave = tid >> 6;
    int wid = blockIdx.x * 4 + wave;
    const double* rs1 = (const double*)(ws + RS1_OFF);
    double rsm1 = *(const double*)(ws + RSM1_OFF);
    int localShift = 0;
    for (int rr = 0; rr < 4; ++rr) {
        size_t base = (size_t)(wid * 4 + rr) * HDIM;
        int q[12];
        int sum = 0;
        #pragma unroll
        for (int c = 0; c < 3; ++c) {
            int4 a = ((const int4*)(buf + base))[lane + 64 * c];
            int w4 = ((const int*)(ws + WX_OFF + base))[lane + 64 * c];
            int o0 = (lane + 64 * c) * 4;
            int av[4] = {a.x, a.y, a.z, a.w};
            #pragma unroll
            for (int j = 0; j < 4; ++j) {
                double q1 = rint((double)av[j] * rs1[o0 + j]);
                int wxj = (int)(char)(w4 >> (8 * j));
                double qq = q1 + rint((double)wxj * rsm1);
                qq = fmin(fmax(qq, -2097152.0), 2097151.0);   // clip [-2^21, 2^21-1]
                q[c * 4 + j] = (int)qq;
                sum += q[c * 4 + j];
            }
        }
        // butterfly reduce: all lanes get the row sum (|sum| <= 768*2^21 < 2^31)
        #pragma unroll
        for (int off = 32; off; off >>= 1) sum += __shfl_xor(sum, off);
        int mean = (int)rint((double)sum / 768.0);    // round-half-even, as jnp.round
        long long var0 = 0;
        #pragma unroll
        for (int k = 0; k < 12; ++k) { q[k] -= mean; var0 += (long long)q[k] * (long long)q[k]; }
        #pragma unroll
        for (int off = 32; off; off >>= 1) var0 += __shfl_xor(var0, off);
        #pragma unroll
        for (int c = 0; c < 3; ++c) {
            int4 y = {q[c * 4 + 0], q[c * 4 + 1], q[c * 4 + 2], q[c * 4 + 3]};
            ((int4*)(buf + base))[lane + 64 * c] = y;
        }
        if (lane == 0) {
            double v = (double)(var0 < 1 ? 1LL : var0);
            int sr = (int)ceil(0.5 * log2(v) - 16.0);     // ceil(log2(sqrt(v/2^32)))
            localShift = max(localShift, sr);
        }
    }
    if (lane == 0 && localShift > 0) {
        int* sp = (int*)(ws + SC_OFF) + 4;
        if (localShift > *(volatile int*)sp) atomicMax(sp, localShift);  // guarded, monotone
    }
}

// ============ K4: wave-per-row IntLayerNorm normalize, hs min/max ============
__global__ __launch_bounds__(256) void k4_rows(char* __restrict__ ws, int* __restrict__ buf) {
    int tid = threadIdx.x, lane = tid & 63, wave = tid >> 6;
    int wid = blockIdx.x * 4 + wave;
    int shift = *(((const int*)(ws + SC_OFF)) + 4);
    const int* lnbi = (const int*)(ws + LNBI_OFF);
    const float* sfo = (const float*)(ws + SFO_OFF);
    float lmn = 3.402823466e38f, lmx = -3.402823466e38f;
    for (int rr = 0; rr < 4; ++rr) {
        size_t base = (size_t)(wid * 4 + rr) * HDIM;
        int yv[12];
        #pragma unroll
        for (int c = 0; c < 3; ++c) {
            int4 y = ((const int4*)(buf + base))[lane + 64 * c];
            yv[c * 4 + 0] = y.x; yv[c * 4 + 1] = y.y; yv[c * 4 + 2] = y.z; yv[c * 4 + 3] = y.w;
        }
        long long var = 0;
        #pragma unroll
        for (int k = 0; k < 12; ++k) { int ysh = yv[k] >> shift; var += (long long)ysh * (long long)ysh; }
        #pragma unroll
        for (int off = 32; off; off >>= 1) var += __shfl_xor(var, off);
        double std_int = floor(sqrt((double)var)) * (double)(1LL << shift);
        if (std_int < 1.0) std_int = 1.0;                 // degenerate-row guard
        long long factor = (long long)floor(2147483648.0 / std_int);
        #pragma unroll
        for (int c = 0; c < 3; ++c) {
            int o0 = (lane + 64 * c) * 4;
            int y2[4];
            #pragma unroll
            for (int j = 0; j < 4; ++j) {
                long long t = ((long long)yv[c * 4 + j] * factor) >> 1;   // floor(y*factor/2)
                int v2 = (int)t + lnbi[o0 + j];
                y2[j] = v2;
                float h = (float)v2 * sfo[o0 + j];
                lmn = fminf(lmn, h);
                lmx = fmaxf(lmx, h);
            }
            int4 w = {y2[0], y2[1], y2[2], y2[3]};
            ((int4*)(buf + base))[lane + 64 * c] = w;
        }
    }
    #pragma unroll
    for (int off = 32; off; off >>= 1) {
        lmn = fminf(lmn, __shfl_xor(lmn, off));
        lmx = fmaxf(lmx, __shfl_xor(lmx, off));
    }
    if (lane == 0) {
        volatile unsigned* sc = (volatile unsigned*)(ws + SC_OFF);
        unsigned emn = fenc(lmn), emx = fenc(lmx);
        if (emn < sc[2]) atomicMin((unsigned*)&sc[2], emn);   // guarded, monotone
        if (emx > sc[3]) atomicMax((unsigned*)&sc[3], emx);
    }
}

// ============ K5: finalize s2 + frexp tables ============
__global__ __launch_bounds__(256) void k5_scale2(char* __restrict__ ws) {
    __shared__ float s_sh;
    unsigned* sc = (unsigned*)(ws + SC_OFF);
    if (threadIdx.x == 0) {
        float mn = fdec(sc[2]), mx = fdec(sc[3]);
        float s2 = fmaxf(fmaxf(fabsf(mn), fabsf(mx)), 1e-8f) / 127.0f;
        ((float*)sc)[6] = s2;
        s_sh = s2;
    }
    __syncthreads();
    float s2 = s_sh;
    const float* sfo = (const float*)(ws + SFO_OFF);
    double* rs2 = (double*)(ws + RS2_OFF);
    for (int o = threadIdx.x; o < HDIM; o += 256) {
        double r = (double)sfo[o] / (double)s2;
        int ex; double mant = frexp(r, &ex);
        double m = floor(mant * 2147483648.0 + 0.5);
        rs2[o] = m * exp2((double)(ex - 31));
    }
}

// ============ K6: 8-bit requant + output write ============
__global__ __launch_bounds__(256) void k6_out(char* __restrict__ ws, float* __restrict__ out) {
    int idx4 = blockIdx.x * 256 + threadIdx.x;
    int4 y = ((const int4*)out)[idx4];
    const double* rs2 = (const double*)(ws + RS2_OFF);
    float s2 = ((const float*)(ws + SC_OFF))[6];
    int base = idx4 * 4;
    int o0 = base % HDIM;   // base%4==0 and 768%4==0 -> no row crossing within int4
    int yv[4] = {y.x, y.y, y.z, y.w};
    float4 r;
    float* rp = &r.x;
    #pragma unroll
    for (int j = 0; j < 4; ++j) {
        double q = rint((double)yv[j] * rs2[o0 + j]);
        q = fmin(fmax(q, -128.0), 127.0);
        rp[j] = (float)q * s2;
    }
    ((float4*)out)[idx4] = r;
    if (idx4 == 0) out[(size_t)NTOK * HDIM] = s2;
}

extern "C" void kernel_launch(void* const* d_in, const int* in_sizes, int n_in,
                              void* d_out, int out_size, void* d_ws, size_t ws_size,
                              hipStream_t stream) {
    const float* hs   = (const float*)d_in[0];
    const float* phsf = (const float*)d_in[1];
    const float* inp  = (const float*)d_in[2];
    const float* pisf = (const float*)d_in[3];
    const float* W    = (const float*)d_in[4];
    const float* bias = (const float*)d_in[5];
    const float* ln_w = (const float*)d_in[6];
    const float* ln_b = (const float*)d_in[7];
    char* ws = (char*)d_ws;
    float* out = (float*)d_out;
    int* buf = (int*)d_out;   // d_out doubles as the 100MB int32 intermediate buffer

    k0_prep<<<HDIM, 256, 0, stream>>>(W, bias, ln_w, ln_b, phsf, ws);
    k1_gemm<<<NTOK / TM, 256, 0, stream>>>(hs, inp, phsf, pisf, ws, buf);
    k2_scale1<<<1, 256, 0, stream>>>(pisf, ws);
    k3_rows<<<NTOK / 16, 256, 0, stream>>>(ws, buf);
    k4_rows<<<NTOK / 16, 256, 0, stream>>>(ws, buf);
    k5_scale2<<<1, 256, 0, stream>>>(ws);
    k6_out<<<NTOK * HDIM / 1024, 256, 0, stream>>>(ws, out);
}

// Round 3
// 547.633 us; speedup vs baseline: 3.3551x; 1.5269x over previous
//
#include <hip/hip_runtime.h>

typedef _Float16 half8 __attribute__((ext_vector_type(8)));
typedef _Float16 half4 __attribute__((ext_vector_type(4)));
typedef float f32x4 __attribute__((ext_vector_type(4)));

#define HDIM 768
#define NTOK 32768

// ---- workspace layout (bytes) ----
static constexpr size_t WX_OFF   = 0;                   // int8  [NTOK*HDIM] = 25165824
static constexpr size_t WINT_OFF = 25165824;            // f16   [HDIM*HDIM] = 1179648 B
static constexpr size_t RS1_OFF  = WINT_OFF + 1179648;  // double[768]
static constexpr size_t RS2_OFF  = RS1_OFF + 6144;      // double[768]
static constexpr size_t BS_OFF   = RS2_OFF + 6144;      // float [768] bias_scale
static constexpr size_t BINT_OFF = BS_OFF + 3072;       // int   [768] b_int
static constexpr size_t LNBI_OFF = BINT_OFF + 3072;     // int   [768] LN bias_int
static constexpr size_t SFO_OFF  = LNBI_OFF + 3072;     // float [768] sf_out
static constexpr size_t SC_OFF   = SFO_OFF + 3072;      // scalars: [0]min1 [1]max1 [2]min2 [3]max2 [4]shift [5]s [6]s2
static constexpr size_t RSM1_OFF = SC_OFF + 64;         // double rs_m1

// sortable-uint encoding of float for atomic min/max
__device__ __forceinline__ unsigned fenc(float f) {
    unsigned u = __float_as_uint(f);
    return (u >> 31) ? ~u : (u | 0x80000000u);
}
__device__ __forceinline__ float fdec(unsigned e) {
    unsigned u = (e >> 31) ? (e & 0x7fffffffu) : ~e;
    return __uint_as_float(u);
}

// async global->LDS, 16B per lane; lds base must be wave-uniform (HW adds lane*16)
#define GLDS16(g, l) __builtin_amdgcn_global_load_lds( \
    (const __attribute__((address_space(1))) unsigned int*)(g), \
    (__attribute__((address_space(3))) unsigned int*)(l), 16, 0, 0)

// ============ K0: weight quantization + per-channel tables + scalar init ============
__global__ __launch_bounds__(256) void k0_prep(const float* __restrict__ W,
                                               const float* __restrict__ bias,
                                               const float* __restrict__ ln_w,
                                               const float* __restrict__ ln_b,
                                               const float* __restrict__ phsf,
                                               char* __restrict__ ws) {
    int o = blockIdx.x, tid = threadIdx.x;
    __shared__ float red[256];
    __shared__ float fc_sh;
    float m = 0.f;
    for (int j = tid; j < HDIM; j += 256) m = fmaxf(m, fabsf(W[(size_t)o * HDIM + j]));
    red[tid] = m;
    __syncthreads();
    for (int s = 128; s; s >>= 1) { if (tid < s) red[tid] = fmaxf(red[tid], red[tid + s]); __syncthreads(); }
    if (tid == 0) {
        float fc = fmaxf(red[0], 1e-8f) / 127.0f;     // _sym_scale(8,...)
        float hsf = *phsf;
        float bs = fc * hsf;
        fc_sh = fc;
        ((float*)(ws + BS_OFF))[o] = bs;
        ((int*)(ws + BINT_OFF))[o] = (int)rintf(bias[o] / bs);   // _sym_quant(bias,32)
        float sf = sqrtf(768.0f) / 1073741824.0f;                // sqrt(H)/2^30
        float lw = ln_w[o], lb = ln_b[o];
        ((int*)(ws + LNBI_OFF))[o] = (int)floorf((lb / lw) / sf);
        ((float*)(ws + SFO_OFF))[o] = sf * lw;
    }
    __syncthreads();
    float fc = fc_sh;
    _Float16* w16 = (_Float16*)(ws + WINT_OFF);
    for (int j = tid; j < HDIM; j += 256) {
        float q = rintf(W[(size_t)o * HDIM + j] / fc);
        q = fminf(fmaxf(q, -127.f), 126.f);           // clip [-n, n-1]
        w16[(size_t)o * HDIM + j] = (_Float16)q;
    }
    if (blockIdx.x == 0 && tid < 8) {
        unsigned* sc = (unsigned*)(ws + SC_OFF);
        unsigned v = 0u;
        if (tid == 0 || tid == 2) v = 0xFFFFFFFFu;    // min slots
        sc[tid] = v;                                   // max slots + shift -> 0
    }
}

// ============ K1: tiled int GEMM (exact, f16 MFMA), double-buffered LDS ============
// BM=128, BN=128, BK=32; grid = (NTOK/128)*6, N-tile-major for A-tile L2 reuse.
// B staged via global_load_lds with XOR-swizzled chunk order (coalesced global,
// conflict-free ds_read_b128); A staged via VGPRs (needs f32->f16-int convert).
#define BM 128
#define BN 128
#define BK 32
#define NKT (HDIM / BK)   // 24
__global__ __launch_bounds__(256) void k1_gemm(const float* __restrict__ hs_in,
                                               const float* __restrict__ inp,
                                               const float* __restrict__ phsf,
                                               const float* __restrict__ pisf,
                                               char* __restrict__ ws,
                                               int* __restrict__ accOut) {
    __shared__ _Float16 As[2][BM][BK + 8];   // padded: frag reads 2-way (free)
    __shared__ _Float16 Bs[2][4096];         // 512 chunks x 8 halves, swizzled
    __shared__ float rmn[4], rmx[4];
    int tid = threadIdx.x;
    int lane = tid & 63, wave = tid >> 6;
    int wrow = lane & 15, wkg = lane >> 4;
    int ntile = blockIdx.x % 6, mtile = blockIdx.x / 6;
    int t0 = mtile * BM, o0 = ntile * BN;
    float inv_hsf = 1.0f / *phsf;
    float inv_isf = 1.0f / *pisf;
    const _Float16* w16 = (const _Float16*)(ws + WINT_OFF);

    // --- B glds addressing: chunk c = i*256 + tid; LDS offset = c*16B.
    // swizzle: row = c>>2, sub = (c&3) ^ (row&3)  -> global reads cover full
    // 64B lines; frag chunk = row*4 + (wkg ^ (row&3)) is 2-way conflict-free.
    int brow0 = tid >> 2,          bsub0 = (tid & 3) ^ (brow0 & 3);
    int brow1 = (256 + tid) >> 2,  bsub1 = ((256 + tid) & 3) ^ (brow1 & 3);
    const _Float16* bsrc0 = w16 + (size_t)(o0 + brow0) * HDIM + bsub0 * 8;
    const _Float16* bsrc1 = w16 + (size_t)(o0 + brow1) * HDIM + bsub1 * 8;
    // wave-uniform LDS bases (HW adds lane*16B)
    int bofs0 = (0 * 256 + wave * 64) * 8;   // halves
    int bofs1 = (1 * 256 + wave * 64) * 8;

    // --- A staging: c = i*256 + tid (i=0..3); row = c>>3, col4 = c&7
    int arow[4], acol4[4];
    #pragma unroll
    for (int i = 0; i < 4; ++i) { int c = i * 256 + tid; arow[i] = c >> 3; acol4[i] = c & 7; }

    // prologue: stage tile 0 into buffer 0
    GLDS16(bsrc0, &Bs[0][bofs0]);
    GLDS16(bsrc1, &Bs[0][bofs1]);
    {
        float4 av[4];
        #pragma unroll
        for (int i = 0; i < 4; ++i)
            av[i] = *(const float4*)(hs_in + (size_t)(t0 + arow[i]) * HDIM + acol4[i] * 4);
        #pragma unroll
        for (int i = 0; i < 4; ++i) {
            half4 h = { (_Float16)rintf(av[i].x * inv_hsf), (_Float16)rintf(av[i].y * inv_hsf),
                        (_Float16)rintf(av[i].z * inv_hsf), (_Float16)rintf(av[i].w * inv_hsf) };
            *(half4*)&As[0][arow[i]][acol4[i] * 4] = h;
        }
    }
    __syncthreads();

    int wm = wave & 1, wn = wave >> 1;
    f32x4 acc[4][4] = {};
    // precomputed LDS frag offsets
    int aofs[4], bfofs[4];
    #pragma unroll
    for (int mi = 0; mi < 4; ++mi) aofs[mi] = wm * 64 + mi * 16 + wrow;
    #pragma unroll
    for (int nf = 0; nf < 4; ++nf) {
        int r = wn * 64 + nf * 16 + wrow;
        bfofs[nf] = (r * 4 + (wkg ^ (r & 3))) * 8;
    }

    for (int kt = 0; kt < NKT; ++kt) {
        int cur = kt & 1, nxt = 1 - cur;
        float4 av[4];
        if (kt < NKT - 1) {
            // issue next tile's loads; they stay in flight during compute
            GLDS16(bsrc0 + (kt + 1) * BK, &Bs[nxt][bofs0]);
            GLDS16(bsrc1 + (kt + 1) * BK, &Bs[nxt][bofs1]);
            #pragma unroll
            for (int i = 0; i < 4; ++i)
                av[i] = *(const float4*)(hs_in + (size_t)(t0 + arow[i]) * HDIM + (kt + 1) * BK + acol4[i] * 4);
        }
        // compute from buffer cur
        half8 af[4], bf[4];
        #pragma unroll
        for (int mi = 0; mi < 4; ++mi) af[mi] = *(const half8*)&As[cur][aofs[mi]][wkg * 8];
        #pragma unroll
        for (int nf = 0; nf < 4; ++nf) bf[nf] = *(const half8*)&Bs[cur][bfofs[nf]];
        #pragma unroll
        for (int mi = 0; mi < 4; ++mi)
            #pragma unroll
            for (int nf = 0; nf < 4; ++nf)
                acc[mi][nf] = __builtin_amdgcn_mfma_f32_16x16x32_f16(af[mi], bf[nf], acc[mi][nf], 0, 0, 0);
        if (kt < NKT - 1) {
            #pragma unroll
            for (int i = 0; i < 4; ++i) {
                half4 h = { (_Float16)rintf(av[i].x * inv_hsf), (_Float16)rintf(av[i].y * inv_hsf),
                            (_Float16)rintf(av[i].z * inv_hsf), (_Float16)rintf(av[i].w * inv_hsf) };
                *(half4*)&As[nxt][arow[i]][acol4[i] * 4] = h;
            }
            __syncthreads();   // waits vmcnt(0): glds for nxt complete + lds writes visible
        }
    }

    // epilogue: bias add, store acc (int32), x_act min/max, wx store
    const float* bscale = (const float*)(ws + BS_OFF);
    const int* bint = (const int*)(ws + BINT_OFF);
    char* wx = (char*)(ws + WX_OFF);
    float lmn = 3.402823466e38f, lmx = -3.402823466e38f;
    #pragma unroll
    for (int mi = 0; mi < 4; ++mi)
        #pragma unroll
        for (int nf = 0; nf < 4; ++nf) {
            int o = o0 + wn * 64 + nf * 16 + wrow;
            int bi = bint[o];
            float bsc = bscale[o];
            #pragma unroll
            for (int r = 0; r < 4; ++r) {
                int t = t0 + wm * 64 + mi * 16 + wkg * 4 + r;
                int a = (int)acc[mi][nf][r] + bi;
                size_t idx = (size_t)t * HDIM + o;
                accOut[idx] = a;
                float xin = inp[idx];
                float xa = (float)a * bsc + xin;
                lmn = fminf(lmn, xa);
                lmx = fmaxf(lmx, xa);
                wx[idx] = (char)rintf(xin * inv_isf);
            }
        }
    #pragma unroll
    for (int off = 32; off; off >>= 1) {
        lmn = fminf(lmn, __shfl_down(lmn, off));
        lmx = fmaxf(lmx, __shfl_down(lmx, off));
    }
    if (lane == 0) { rmn[wave] = lmn; rmx[wave] = lmx; }
    __syncthreads();
    if (tid == 0) {
        float mn = fminf(fminf(rmn[0], rmn[1]), fminf(rmn[2], rmn[3]));
        float mx = fmaxf(fmaxf(rmx[0], rmx[1]), fmaxf(rmx[2], rmx[3]));
        volatile unsigned* sc = (volatile unsigned*)(ws + SC_OFF);
        unsigned emn = fenc(mn), emx = fenc(mx);
        if (emn < sc[0]) atomicMin((unsigned*)&sc[0], emn);   // guarded, monotone
        if (emx > sc[1]) atomicMax((unsigned*)&sc[1], emx);
    }
}

// ============ K2: finalize ln_in_scale s + frexp tables ============
__global__ __launch_bounds__(256) void k2_scale1(const float* __restrict__ pisf, char* __restrict__ ws) {
    __shared__ float s_sh;
    unsigned* sc = (unsigned*)(ws + SC_OFF);
    if (threadIdx.x == 0) {
        float mn = fdec(sc[0]), mx = fdec(sc[1]);
        float s = fmaxf(fmaxf(fabsf(mn), fabsf(mx)), 1e-8f) / 2097151.0f;  // n = 2^21-1
        ((float*)sc)[5] = s;
        s_sh = s;
        double r = (double)(*pisf) / (double)s;
        int ex; double mant = frexp(r, &ex);
        double m1 = floor(mant * 2147483648.0 + 0.5);
        ((double*)(ws + RSM1_OFF))[0] = m1 * exp2((double)(ex - 31));  // m1 * 2^-(31-ex)
    }
    __syncthreads();
    float s = s_sh;
    const float* bs = (const float*)(ws + BS_OFF);
    double* rs1 = (double*)(ws + RS1_OFF);
    for (int o = threadIdx.x; o < HDIM; o += 256) {
        double r = (double)bs[o] / (double)s;
        int ex; double mant = frexp(r, &ex);
        double m = floor(mant * 2147483648.0 + 0.5);
        rs1[o] = m * exp2((double)(ex - 31));
    }
}

// ============ K3: wave-per-row fixed-point requant (22-bit), mean, var0, shift ============
__global__ __launch_bounds__(256) void k3_rows(char* __restrict__ ws, int* __restrict__ buf) {
    int tid = threadIdx.x, lane = tid & 63, wave = tid >> 6;
    int wid = blockIdx.x * 4 + wave;
    const double* rs1 = (const double*)(ws + RS1_OFF);
    double rsm1 = *(const double*)(ws + RSM1_OFF);
    int localShift = 0;
    for (int rr = 0; rr < 4; ++rr) {
        size_t base = (size_t)(wid * 4 + rr) * HDIM;
        int q[12];
        int sum = 0;
        #pragma unroll
        for (int c = 0; c < 3; ++c) {
            int4 a = ((const int4*)(buf + base))[lane + 64 * c];
            int w4 = ((const int*)(ws + WX_OFF + base))[lane + 64 * c];
            int o0 = (lane + 64 * c) * 4;
            int av[4] = {a.x, a.y, a.z, a.w};
            #pragma unroll
            for (int j = 0; j < 4; ++j) {
                double q1 = rint((double)av[j] * rs1[o0 + j]);
                int wxj = (int)(char)(w4 >> (8 * j));
                double qq = q1 + rint((double)wxj * rsm1);
                qq = fmin(fmax(qq, -2097152.0), 2097151.0);   // clip [-2^21, 2^21-1]
                q[c * 4 + j] = (int)qq;
                sum += q[c * 4 + j];
            }
        }
        #pragma unroll
        for (int off = 32; off; off >>= 1) sum += __shfl_xor(sum, off);
        int mean = (int)rint((double)sum / 768.0);
        long long var0 = 0;
        #pragma unroll
        for (int k = 0; k < 12; ++k) { q[k] -= mean; var0 += (long long)q[k] * (long long)q[k]; }
        #pragma unroll
        for (int off = 32; off; off >>= 1) var0 += __shfl_xor(var0, off);
        #pragma unroll
        for (int c = 0; c < 3; ++c) {
            int4 y = {q[c * 4 + 0], q[c * 4 + 1], q[c * 4 + 2], q[c * 4 + 3]};
            ((int4*)(buf + base))[lane + 64 * c] = y;
        }
        if (lane == 0) {
            double v = (double)(var0 < 1 ? 1LL : var0);
            int sr = (int)ceil(0.5 * log2(v) - 16.0);     // ceil(log2(sqrt(v/2^32)))
            localShift = max(localShift, sr);
        }
    }
    if (lane == 0 && localShift > 0) {
        int* sp = (int*)(ws + SC_OFF) + 4;
        if (localShift > *(volatile int*)sp) atomicMax(sp, localShift);  // guarded, monotone
    }
}

// ============ K4: wave-per-row IntLayerNorm normalize, hs min/max ============
__global__ __launch_bounds__(256) void k4_rows(char* __restrict__ ws, int* __restrict__ buf) {
    int tid = threadIdx.x, lane = tid & 63, wave = tid >> 6;
    int wid = blockIdx.x * 4 + wave;
    int shift = *(((const int*)(ws + SC_OFF)) + 4);
    const int* lnbi = (const int*)(ws + LNBI_OFF);
    const float* sfo = (const float*)(ws + SFO_OFF);
    float lmn = 3.402823466e38f, lmx = -3.402823466e38f;
    for (int rr = 0; rr < 4; ++rr) {
        size_t base = (size_t)(wid * 4 + rr) * HDIM;
        int yv[12];
        #pragma unroll
        for (int c = 0; c < 3; ++c) {
            int4 y = ((const int4*)(buf + base))[lane + 64 * c];
            yv[c * 4 + 0] = y.x; yv[c * 4 + 1] = y.y; yv[c * 4 + 2] = y.z; yv[c * 4 + 3] = y.w;
        }
        long long var = 0;
        #pragma unroll
        for (int k = 0; k < 12; ++k) { int ysh = yv[k] >> shift; var += (long long)ysh * (long long)ysh; }
        #pragma unroll
        for (int off = 32; off; off >>= 1) var += __shfl_xor(var, off);
        double std_int = floor(sqrt((double)var)) * (double)(1LL << shift);
        if (std_int < 1.0) std_int = 1.0;                 // degenerate-row guard
        long long factor = (long long)floor(2147483648.0 / std_int);
        #pragma unroll
        for (int c = 0; c < 3; ++c) {
            int o0 = (lane + 64 * c) * 4;
            int y2[4];
            #pragma unroll
            for (int j = 0; j < 4; ++j) {
                long long t = ((long long)yv[c * 4 + j] * factor) >> 1;   // floor(y*factor/2)
                int v2 = (int)t + lnbi[o0 + j];
                y2[j] = v2;
                float h = (float)v2 * sfo[o0 + j];
                lmn = fminf(lmn, h);
                lmx = fmaxf(lmx, h);
            }
            int4 w = {y2[0], y2[1], y2[2], y2[3]};
            ((int4*)(buf + base))[lane + 64 * c] = w;
        }
    }
    #pragma unroll
    for (int off = 32; off; off >>= 1) {
        lmn = fminf(lmn, __shfl_xor(lmn, off));
        lmx = fmaxf(lmx, __shfl_xor(lmx, off));
    }
    if (lane == 0) {
        volatile unsigned* sc = (volatile unsigned*)(ws + SC_OFF);
        unsigned emn = fenc(lmn), emx = fenc(lmx);
        if (emn < sc[2]) atomicMin((unsigned*)&sc[2], emn);   // guarded, monotone
        if (emx > sc[3]) atomicMax((unsigned*)&sc[3], emx);
    }
}

// ============ K5: finalize s2 + frexp tables ============
__global__ __launch_bounds__(256) void k5_scale2(char* __restrict__ ws) {
    __shared__ float s_sh;
    unsigned* sc = (unsigned*)(ws + SC_OFF);
    if (threadIdx.x == 0) {
        float mn = fdec(sc[2]), mx = fdec(sc[3]);
        float s2 = fmaxf(fmaxf(fabsf(mn), fabsf(mx)), 1e-8f) / 127.0f;
        ((float*)sc)[6] = s2;
        s_sh = s2;
    }
    __syncthreads();
    float s2 = s_sh;
    const float* sfo = (const float*)(ws + SFO_OFF);
    double* rs2 = (double*)(ws + RS2_OFF);
    for (int o = threadIdx.x; o < HDIM; o += 256) {
        double r = (double)sfo[o] / (double)s2;
        int ex; double mant = frexp(r, &ex);
        double m = floor(mant * 2147483648.0 + 0.5);
        rs2[o] = m * exp2((double)(ex - 31));
    }
}

// ============ K6: 8-bit requant + output write ============
__global__ __launch_bounds__(256) void k6_out(char* __restrict__ ws, float* __restrict__ out) {
    int idx4 = blockIdx.x * 256 + threadIdx.x;
    int4 y = ((const int4*)out)[idx4];
    const double* rs2 = (const double*)(ws + RS2_OFF);
    float s2 = ((const float*)(ws + SC_OFF))[6];
    int base = idx4 * 4;
    int o0 = base % HDIM;
    int yv[4] = {y.x, y.y, y.z, y.w};
    float4 r;
    float* rp = &r.x;
    #pragma unroll
    for (int j = 0; j < 4; ++j) {
        double q = rint((double)yv[j] * rs2[o0 + j]);
        q = fmin(fmax(q, -128.0), 127.0);
        rp[j] = (float)q * s2;
    }
    ((float4*)out)[idx4] = r;
    if (idx4 == 0) out[(size_t)NTOK * HDIM] = s2;
}

extern "C" void kernel_launch(void* const* d_in, const int* in_sizes, int n_in,
                              void* d_out, int out_size, void* d_ws, size_t ws_size,
                              hipStream_t stream) {
    const float* hs   = (const float*)d_in[0];
    const float* phsf = (const float*)d_in[1];
    const float* inp  = (const float*)d_in[2];
    const float* pisf = (const float*)d_in[3];
    const float* W    = (const float*)d_in[4];
    const float* bias = (const float*)d_in[5];
    const float* ln_w = (const float*)d_in[6];
    const float* ln_b = (const float*)d_in[7];
    char* ws = (char*)d_ws;
    float* out = (float*)d_out;
    int* buf = (int*)d_out;   // d_out doubles as the 100MB int32 intermediate buffer

    k0_prep<<<HDIM, 256, 0, stream>>>(W, bias, ln_w, ln_b, phsf, ws);
    k1_gemm<<<(NTOK / BM) * (HDIM / BN), 256, 0, stream>>>(hs, inp, phsf, pisf, ws, buf);
    k2_scale1<<<1, 256, 0, stream>>>(pisf, ws);
    k3_rows<<<NTOK / 16, 256, 0, stream>>>(ws, buf);
    k4_rows<<<NTOK / 16, 256, 0, stream>>>(ws, buf);
    k5_scale2<<<1, 256, 0, stream>>>(ws);
    k6_out<<<NTOK * HDIM / 1024, 256, 0, stream>>>(ws, out);
}

// Round 4
// 513.244 us; speedup vs baseline: 3.5799x; 1.0670x over previous
//
#include <hip/hip_runtime.h>

typedef _Float16 half8 __attribute__((ext_vector_type(8)));
typedef _Float16 half4 __attribute__((ext_vector_type(4)));
typedef float f32x4 __attribute__((ext_vector_type(4)));

#define HDIM 768
#define NTOK 32768

// ---- workspace layout (bytes) ----
static constexpr size_t WX_OFF   = 0;                   // int8  [NTOK*HDIM] = 25165824
static constexpr size_t WINT_OFF = 25165824;            // f16   [HDIM*HDIM] = 1179648 B
static constexpr size_t RS1_OFF  = WINT_OFF + 1179648;  // double[768]
static constexpr size_t RS2_OFF  = RS1_OFF + 6144;      // double[768]
static constexpr size_t BS_OFF   = RS2_OFF + 6144;      // float [768] bias_scale
static constexpr size_t BINT_OFF = BS_OFF + 3072;       // int   [768] b_int
static constexpr size_t LNBI_OFF = BINT_OFF + 3072;     // int   [768] LN bias_int
static constexpr size_t SFO_OFF  = LNBI_OFF + 3072;     // float [768] sf_out
static constexpr size_t SC_OFF   = SFO_OFF + 3072;      // scalars: [0]min1 [1]max1 [2]min2 [3]max2 [4]shift [5]s [6]s2
static constexpr size_t RSM1_OFF = SC_OFF + 64;         // double rs_m1

// sortable-uint encoding of float for atomic min/max
__device__ __forceinline__ unsigned fenc(float f) {
    unsigned u = __float_as_uint(f);
    return (u >> 31) ? ~u : (u | 0x80000000u);
}
__device__ __forceinline__ float fdec(unsigned e) {
    unsigned u = (e >> 31) ? (e & 0x7fffffffu) : ~e;
    return __uint_as_float(u);
}

// async global->LDS, 16B per lane; lds base must be wave-uniform (HW adds lane*16)
#define GLDS16(g, l) __builtin_amdgcn_global_load_lds( \
    (const __attribute__((address_space(1))) unsigned int*)(g), \
    (__attribute__((address_space(3))) unsigned int*)(l), 16, 0, 0)

// ============ K0: weight quantization + per-channel tables + scalar init ============
__global__ __launch_bounds__(256) void k0_prep(const float* __restrict__ W,
                                               const float* __restrict__ bias,
                                               const float* __restrict__ ln_w,
                                               const float* __restrict__ ln_b,
                                               const float* __restrict__ phsf,
                                               char* __restrict__ ws) {
    int o = blockIdx.x, tid = threadIdx.x;
    __shared__ float red[256];
    __shared__ float fc_sh;
    float m = 0.f;
    for (int j = tid; j < HDIM; j += 256) m = fmaxf(m, fabsf(W[(size_t)o * HDIM + j]));
    red[tid] = m;
    __syncthreads();
    for (int s = 128; s; s >>= 1) { if (tid < s) red[tid] = fmaxf(red[tid], red[tid + s]); __syncthreads(); }
    if (tid == 0) {
        float fc = fmaxf(red[0], 1e-8f) / 127.0f;     // _sym_scale(8,...)
        float hsf = *phsf;
        float bs = fc * hsf;
        fc_sh = fc;
        ((float*)(ws + BS_OFF))[o] = bs;
        ((int*)(ws + BINT_OFF))[o] = (int)rintf(bias[o] / bs);   // _sym_quant(bias,32)
        float sf = sqrtf(768.0f) / 1073741824.0f;                // sqrt(H)/2^30
        float lw = ln_w[o], lb = ln_b[o];
        ((int*)(ws + LNBI_OFF))[o] = (int)floorf((lb / lw) / sf);
        ((float*)(ws + SFO_OFF))[o] = sf * lw;
    }
    __syncthreads();
    float fc = fc_sh;
    _Float16* w16 = (_Float16*)(ws + WINT_OFF);
    for (int j = tid; j < HDIM; j += 256) {
        float q = rintf(W[(size_t)o * HDIM + j] / fc);
        q = fminf(fmaxf(q, -127.f), 126.f);           // clip [-n, n-1]
        w16[(size_t)o * HDIM + j] = (_Float16)q;
    }
    if (blockIdx.x == 0 && tid < 8) {
        unsigned* sc = (unsigned*)(ws + SC_OFF);
        unsigned v = 0u;
        if (tid == 0 || tid == 2) v = 0xFFFFFFFFu;    // min slots
        sc[tid] = v;                                   // max slots + shift -> 0
    }
}

// ============ K1: tiled int GEMM (exact, f16 MFMA), double-buffered LDS ============
// BM=128, BN=128, BK=32; grid = 1536. XCD-aware remap: blocks are dispatched
// round-robin over 8 XCDs (bid&7); we give each XCD a contiguous set of 32
// mtiles so the 6 ntile-blocks sharing an A-tile are co-resident on one XCD
// and A is fetched from HBM once globally (L2 serves the other 5).
#define BM 128
#define BN 128
#define BK 32
#define NKT (HDIM / BK)   // 24
__global__ __launch_bounds__(256) void k1_gemm(const float* __restrict__ hs_in,
                                               const float* __restrict__ inp,
                                               const float* __restrict__ phsf,
                                               const float* __restrict__ pisf,
                                               char* __restrict__ ws,
                                               int* __restrict__ accOut) {
    __shared__ _Float16 As[2][BM][BK + 8];   // padded: frag reads 2-way (free)
    __shared__ _Float16 Bs[2][4096];         // 512 chunks x 8 halves, swizzled
    __shared__ float rmn[4], rmx[4];
    int tid = threadIdx.x;
    int lane = tid & 63, wave = tid >> 6;
    int wrow = lane & 15, wkg = lane >> 4;
    // XCD-aware remap (perf heuristic only; correctness mapping-independent)
    int bid = blockIdx.x;
    int xcd = bid & 7, slot = bid >> 3;       // 8 XCDs x 192 slots
    int mtile = xcd * 32 + slot / 6;          // 32 mtiles per XCD
    int ntile = slot % 6;
    int t0 = mtile * BM, o0 = ntile * BN;
    float inv_hsf = 1.0f / *phsf;
    float inv_isf = 1.0f / *pisf;
    const _Float16* w16 = (const _Float16*)(ws + WINT_OFF);

    // --- B glds addressing: chunk c = i*256 + tid; LDS offset = c*16B.
    // swizzle: row = c>>2, sub = (c&3) ^ (row&3)  -> global reads cover full
    // 64B lines; frag chunk = row*4 + (wkg ^ (row&3)).
    int brow0 = tid >> 2,          bsub0 = (tid & 3) ^ (brow0 & 3);
    int brow1 = (256 + tid) >> 2,  bsub1 = ((256 + tid) & 3) ^ (brow1 & 3);
    const _Float16* bsrc0 = w16 + (size_t)(o0 + brow0) * HDIM + bsub0 * 8;
    const _Float16* bsrc1 = w16 + (size_t)(o0 + brow1) * HDIM + bsub1 * 8;
    // wave-uniform LDS bases (HW adds lane*16B)
    int bofs0 = (0 * 256 + wave * 64) * 8;   // halves
    int bofs1 = (1 * 256 + wave * 64) * 8;

    // --- A staging: c = i*256 + tid (i=0..3); row = c>>3, col4 = c&7
    int arow[4], acol4[4];
    #pragma unroll
    for (int i = 0; i < 4; ++i) { int c = i * 256 + tid; arow[i] = c >> 3; acol4[i] = c & 7; }

    // prologue: stage tile 0 into buffer 0
    GLDS16(bsrc0, &Bs[0][bofs0]);
    GLDS16(bsrc1, &Bs[0][bofs1]);
    {
        float4 av[4];
        #pragma unroll
        for (int i = 0; i < 4; ++i)
            av[i] = *(const float4*)(hs_in + (size_t)(t0 + arow[i]) * HDIM + acol4[i] * 4);
        #pragma unroll
        for (int i = 0; i < 4; ++i) {
            half4 h = { (_Float16)rintf(av[i].x * inv_hsf), (_Float16)rintf(av[i].y * inv_hsf),
                        (_Float16)rintf(av[i].z * inv_hsf), (_Float16)rintf(av[i].w * inv_hsf) };
            *(half4*)&As[0][arow[i]][acol4[i] * 4] = h;
        }
    }
    __syncthreads();

    int wm = wave & 1, wn = wave >> 1;
    f32x4 acc[4][4] = {};
    // precomputed LDS frag offsets
    int aofs[4], bfofs[4];
    #pragma unroll
    for (int mi = 0; mi < 4; ++mi) aofs[mi] = wm * 64 + mi * 16 + wrow;
    #pragma unroll
    for (int nf = 0; nf < 4; ++nf) {
        int r = wn * 64 + nf * 16 + wrow;
        bfofs[nf] = (r * 4 + (wkg ^ (r & 3))) * 8;
    }

    for (int kt = 0; kt < NKT; ++kt) {
        int cur = kt & 1, nxt = 1 - cur;
        float4 av[4];
        if (kt < NKT - 1) {
            // issue next tile's loads; they stay in flight during compute
            GLDS16(bsrc0 + (kt + 1) * BK, &Bs[nxt][bofs0]);
            GLDS16(bsrc1 + (kt + 1) * BK, &Bs[nxt][bofs1]);
            #pragma unroll
            for (int i = 0; i < 4; ++i)
                av[i] = *(const float4*)(hs_in + (size_t)(t0 + arow[i]) * HDIM + (kt + 1) * BK + acol4[i] * 4);
        }
        // compute from buffer cur
        half8 af[4], bf[4];
        #pragma unroll
        for (int mi = 0; mi < 4; ++mi) af[mi] = *(const half8*)&As[cur][aofs[mi]][wkg * 8];
        #pragma unroll
        for (int nf = 0; nf < 4; ++nf) bf[nf] = *(const half8*)&Bs[cur][bfofs[nf]];
        #pragma unroll
        for (int mi = 0; mi < 4; ++mi)
            #pragma unroll
            for (int nf = 0; nf < 4; ++nf)
                acc[mi][nf] = __builtin_amdgcn_mfma_f32_16x16x32_f16(af[mi], bf[nf], acc[mi][nf], 0, 0, 0);
        if (kt < NKT - 1) {
            #pragma unroll
            for (int i = 0; i < 4; ++i) {
                half4 h = { (_Float16)rintf(av[i].x * inv_hsf), (_Float16)rintf(av[i].y * inv_hsf),
                            (_Float16)rintf(av[i].z * inv_hsf), (_Float16)rintf(av[i].w * inv_hsf) };
                *(half4*)&As[nxt][arow[i]][acol4[i] * 4] = h;
            }
            __syncthreads();   // waits vmcnt(0): glds for nxt complete + lds writes visible
        }
    }

    // epilogue: bias add, store acc (int32), x_act min/max, wx store
    const float* bscale = (const float*)(ws + BS_OFF);
    const int* bint = (const int*)(ws + BINT_OFF);
    char* wx = (char*)(ws + WX_OFF);
    float lmn = 3.402823466e38f, lmx = -3.402823466e38f;
    #pragma unroll
    for (int mi = 0; mi < 4; ++mi)
        #pragma unroll
        for (int nf = 0; nf < 4; ++nf) {
            int o = o0 + wn * 64 + nf * 16 + wrow;
            int bi = bint[o];
            float bsc = bscale[o];
            #pragma unroll
            for (int r = 0; r < 4; ++r) {
                int t = t0 + wm * 64 + mi * 16 + wkg * 4 + r;
                int a = (int)acc[mi][nf][r] + bi;
                size_t idx = (size_t)t * HDIM + o;
                accOut[idx] = a;
                float xin = inp[idx];
                float xa = (float)a * bsc + xin;
                lmn = fminf(lmn, xa);
                lmx = fmaxf(lmx, xa);
                wx[idx] = (char)rintf(xin * inv_isf);
            }
        }
    #pragma unroll
    for (int off = 32; off; off >>= 1) {
        lmn = fminf(lmn, __shfl_down(lmn, off));
        lmx = fmaxf(lmx, __shfl_down(lmx, off));
    }
    if (lane == 0) { rmn[wave] = lmn; rmx[wave] = lmx; }
    __syncthreads();
    if (tid == 0) {
        float mn = fminf(fminf(rmn[0], rmn[1]), fminf(rmn[2], rmn[3]));
        float mx = fmaxf(fmaxf(rmx[0], rmx[1]), fmaxf(rmx[2], rmx[3]));
        volatile unsigned* sc = (volatile unsigned*)(ws + SC_OFF);
        unsigned emn = fenc(mn), emx = fenc(mx);
        if (emn < sc[0]) atomicMin((unsigned*)&sc[0], emn);   // guarded, monotone
        if (emx > sc[1]) atomicMax((unsigned*)&sc[1], emx);
    }
}

// ============ K2: finalize ln_in_scale s + frexp tables ============
__global__ __launch_bounds__(256) void k2_scale1(const float* __restrict__ pisf, char* __restrict__ ws) {
    __shared__ float s_sh;
    unsigned* sc = (unsigned*)(ws + SC_OFF);
    if (threadIdx.x == 0) {
        float mn = fdec(sc[0]), mx = fdec(sc[1]);
        float s = fmaxf(fmaxf(fabsf(mn), fabsf(mx)), 1e-8f) / 2097151.0f;  // n = 2^21-1
        ((float*)sc)[5] = s;
        s_sh = s;
        double r = (double)(*pisf) / (double)s;
        int ex; double mant = frexp(r, &ex);
        double m1 = floor(mant * 2147483648.0 + 0.5);
        ((double*)(ws + RSM1_OFF))[0] = m1 * exp2((double)(ex - 31));  // m1 * 2^-(31-ex)
    }
    __syncthreads();
    float s = s_sh;
    const float* bs = (const float*)(ws + BS_OFF);
    double* rs1 = (double*)(ws + RS1_OFF);
    for (int o = threadIdx.x; o < HDIM; o += 256) {
        double r = (double)bs[o] / (double)s;
        int ex; double mant = frexp(r, &ex);
        double m = floor(mant * 2147483648.0 + 0.5);
        rs1[o] = m * exp2((double)(ex - 31));
    }
}

// ============ K3: wave-per-row fixed-point requant (22-bit), pipelined rows ============
__global__ __launch_bounds__(256) void k3_rows(char* __restrict__ ws, int* __restrict__ buf) {
    int tid = threadIdx.x, lane = tid & 63, wave = tid >> 6;
    int wid = blockIdx.x * 4 + wave;
    const double* rs1 = (const double*)(ws + RS1_OFF);
    double rsm1 = *(const double*)(ws + RSM1_OFF);
    int localShift = 0;
    // preload row 0
    int4 aP[3]; int wP[3];
    {
        size_t b0 = (size_t)(wid * 4) * HDIM;
        #pragma unroll
        for (int c = 0; c < 3; ++c) {
            aP[c] = ((const int4*)(buf + b0))[lane + 64 * c];
            wP[c] = ((const int*)(ws + WX_OFF + b0))[lane + 64 * c];
        }
    }
    for (int rr = 0; rr < 4; ++rr) {
        int4 aN[3]; int wN[3];
        if (rr < 3) {   // issue next row's loads; overlap with this row's math
            size_t nb = (size_t)(wid * 4 + rr + 1) * HDIM;
            #pragma unroll
            for (int c = 0; c < 3; ++c) {
                aN[c] = ((const int4*)(buf + nb))[lane + 64 * c];
                wN[c] = ((const int*)(ws + WX_OFF + nb))[lane + 64 * c];
            }
        }
        size_t base = (size_t)(wid * 4 + rr) * HDIM;
        int q[12];
        int sum = 0;
        #pragma unroll
        for (int c = 0; c < 3; ++c) {
            int o0 = (lane + 64 * c) * 4;
            int av[4] = {aP[c].x, aP[c].y, aP[c].z, aP[c].w};
            #pragma unroll
            for (int j = 0; j < 4; ++j) {
                double q1 = rint((double)av[j] * rs1[o0 + j]);
                int wxj = (int)(char)(wP[c] >> (8 * j));
                double qq = q1 + rint((double)wxj * rsm1);
                qq = fmin(fmax(qq, -2097152.0), 2097151.0);   // clip [-2^21, 2^21-1]
                q[c * 4 + j] = (int)qq;
                sum += q[c * 4 + j];
            }
        }
        #pragma unroll
        for (int off = 32; off; off >>= 1) sum += __shfl_xor(sum, off);
        int mean = (int)rint((double)sum / 768.0);
        long long var0 = 0;
        #pragma unroll
        for (int k = 0; k < 12; ++k) { q[k] -= mean; var0 += (long long)q[k] * (long long)q[k]; }
        #pragma unroll
        for (int off = 32; off; off >>= 1) var0 += __shfl_xor(var0, off);
        #pragma unroll
        for (int c = 0; c < 3; ++c) {
            int4 y = {q[c * 4 + 0], q[c * 4 + 1], q[c * 4 + 2], q[c * 4 + 3]};
            ((int4*)(buf + base))[lane + 64 * c] = y;
        }
        if (lane == 0) {
            double v = (double)(var0 < 1 ? 1LL : var0);
            int sr = (int)ceil(0.5 * log2(v) - 16.0);     // ceil(log2(sqrt(v/2^32)))
            localShift = max(localShift, sr);
        }
        #pragma unroll
        for (int c = 0; c < 3; ++c) { aP[c] = aN[c]; wP[c] = wN[c]; }
    }
    if (lane == 0 && localShift > 0) {
        int* sp = (int*)(ws + SC_OFF) + 4;
        if (localShift > *(volatile int*)sp) atomicMax(sp, localShift);  // guarded, monotone
    }
}

// ============ K4: wave-per-row IntLayerNorm normalize, pipelined rows ============
__global__ __launch_bounds__(256) void k4_rows(char* __restrict__ ws, int* __restrict__ buf) {
    int tid = threadIdx.x, lane = tid & 63, wave = tid >> 6;
    int wid = blockIdx.x * 4 + wave;
    int shift = *(((const int*)(ws + SC_OFF)) + 4);
    const int* lnbi = (const int*)(ws + LNBI_OFF);
    const float* sfo = (const float*)(ws + SFO_OFF);
    float lmn = 3.402823466e38f, lmx = -3.402823466e38f;
    int4 yP[3];
    {
        size_t b0 = (size_t)(wid * 4) * HDIM;
        #pragma unroll
        for (int c = 0; c < 3; ++c) yP[c] = ((const int4*)(buf + b0))[lane + 64 * c];
    }
    for (int rr = 0; rr < 4; ++rr) {
        int4 yN[3];
        if (rr < 3) {
            size_t nb = (size_t)(wid * 4 + rr + 1) * HDIM;
            #pragma unroll
            for (int c = 0; c < 3; ++c) yN[c] = ((const int4*)(buf + nb))[lane + 64 * c];
        }
        size_t base = (size_t)(wid * 4 + rr) * HDIM;
        int yv[12];
        #pragma unroll
        for (int c = 0; c < 3; ++c) {
            yv[c * 4 + 0] = yP[c].x; yv[c * 4 + 1] = yP[c].y; yv[c * 4 + 2] = yP[c].z; yv[c * 4 + 3] = yP[c].w;
        }
        long long var = 0;
        #pragma unroll
        for (int k = 0; k < 12; ++k) { int ysh = yv[k] >> shift; var += (long long)ysh * (long long)ysh; }
        #pragma unroll
        for (int off = 32; off; off >>= 1) var += __shfl_xor(var, off);
        double std_int = floor(sqrt((double)var)) * (double)(1LL << shift);
        if (std_int < 1.0) std_int = 1.0;                 // degenerate-row guard
        long long factor = (long long)floor(2147483648.0 / std_int);
        #pragma unroll
        for (int c = 0; c < 3; ++c) {
            int o0 = (lane + 64 * c) * 4;
            int y2[4];
            #pragma unroll
            for (int j = 0; j < 4; ++j) {
                long long t = ((long long)yv[c * 4 + j] * factor) >> 1;   // floor(y*factor/2)
                int v2 = (int)t + lnbi[o0 + j];
                y2[j] = v2;
                float h = (float)v2 * sfo[o0 + j];
                lmn = fminf(lmn, h);
                lmx = fmaxf(lmx, h);
            }
            int4 w = {y2[0], y2[1], y2[2], y2[3]};
            ((int4*)(buf + base))[lane + 64 * c] = w;
        }
        #pragma unroll
        for (int c = 0; c < 3; ++c) yP[c] = yN[c];
    }
    #pragma unroll
    for (int off = 32; off; off >>= 1) {
        lmn = fminf(lmn, __shfl_xor(lmn, off));
        lmx = fmaxf(lmx, __shfl_xor(lmx, off));
    }
    if (lane == 0) {
        volatile unsigned* sc = (volatile unsigned*)(ws + SC_OFF);
        unsigned emn = fenc(lmn), emx = fenc(lmx);
        if (emn < sc[2]) atomicMin((unsigned*)&sc[2], emn);   // guarded, monotone
        if (emx > sc[3]) atomicMax((unsigned*)&sc[3], emx);
    }
}

// ============ K5: finalize s2 + frexp tables ============
__global__ __launch_bounds__(256) void k5_scale2(char* __restrict__ ws) {
    __shared__ float s_sh;
    unsigned* sc = (unsigned*)(ws + SC_OFF);
    if (threadIdx.x == 0) {
        float mn = fdec(sc[2]), mx = fdec(sc[3]);
        float s2 = fmaxf(fmaxf(fabsf(mn), fabsf(mx)), 1e-8f) / 127.0f;
        ((float*)sc)[6] = s2;
        s_sh = s2;
    }
    __syncthreads();
    float s2 = s_sh;
    const float* sfo = (const float*)(ws + SFO_OFF);
    double* rs2 = (double*)(ws + RS2_OFF);
    for (int o = threadIdx.x; o < HDIM; o += 256) {
        double r = (double)sfo[o] / (double)s2;
        int ex; double mant = frexp(r, &ex);
        double m = floor(mant * 2147483648.0 + 0.5);
        rs2[o] = m * exp2((double)(ex - 31));
    }
}

// ============ K6: 8-bit requant + output write ============
__global__ __launch_bounds__(256) void k6_out(char* __restrict__ ws, float* __restrict__ out) {
    int idx4 = blockIdx.x * 256 + threadIdx.x;
    int4 y = ((const int4*)out)[idx4];
    const double* rs2 = (const double*)(ws + RS2_OFF);
    float s2 = ((const float*)(ws + SC_OFF))[6];
    int base = idx4 * 4;
    int o0 = base % HDIM;
    int yv[4] = {y.x, y.y, y.z, y.w};
    float4 r;
    float* rp = &r.x;
    #pragma unroll
    for (int j = 0; j < 4; ++j) {
        double q = rint((double)yv[j] * rs2[o0 + j]);
        q = fmin(fmax(q, -128.0), 127.0);
        rp[j] = (float)q * s2;
    }
    ((float4*)out)[idx4] = r;
    if (idx4 == 0) out[(size_t)NTOK * HDIM] = s2;
}

extern "C" void kernel_launch(void* const* d_in, const int* in_sizes, int n_in,
                              void* d_out, int out_size, void* d_ws, size_t ws_size,
                              hipStream_t stream) {
    const float* hs   = (const float*)d_in[0];
    const float* phsf = (const float*)d_in[1];
    const float* inp  = (const float*)d_in[2];
    const float* pisf = (const float*)d_in[3];
    const float* W    = (const float*)d_in[4];
    const float* bias = (const float*)d_in[5];
    const float* ln_w = (const float*)d_in[6];
    const float* ln_b = (const float*)d_in[7];
    char* ws = (char*)d_ws;
    float* out = (float*)d_out;
    int* buf = (int*)d_out;   // d_out doubles as the 100MB int32 intermediate buffer

    k0_prep<<<HDIM, 256, 0, stream>>>(W, bias, ln_w, ln_b, phsf, ws);
    k1_gemm<<<(NTOK / BM) * (HDIM / BN), 256, 0, stream>>>(hs, inp, phsf, pisf, ws, buf);
    k2_scale1<<<1, 256, 0, stream>>>(pisf, ws);
    k3_rows<<<NTOK / 16, 256, 0, stream>>>(ws, buf);
    k4_rows<<<NTOK / 16, 256, 0, stream>>>(ws, buf);
    k5_scale2<<<1, 256, 0, stream>>>(ws);
    k6_out<<<NTOK * HDIM / 1024, 256, 0, stream>>>(ws, out);
}